// Round 3
// baseline (326.384 us; speedup 1.0000x reference)
//
#include <hip/hip_runtime.h>
#include <hip/hip_bf16.h>
#include <stdint.h>

#define IC 32
#define OC 32
#define NREG 33      // 32 hinges -> 33 piecewise-linear regions
#define NPB 200      // nodes per bucket (LDS accumulator = NPB*32 floats)
#define ECAP 2048    // per-chunk edge staging capacity in LDS

typedef __attribute__((ext_vector_type(8))) short short8;
typedef __attribute__((ext_vector_type(4))) float f32x4;

static __device__ __forceinline__ short f2bf(float f) {
    __bf16 b = (__bf16)f;
    return __builtin_bit_cast(short, b);
}

// ===========================================================================
// Piecewise-linear setup (validated in round 2):
// h_k(t)=relu(t*w1[k]+b1[k]) linear within regions bounded by hinges
// t_k=-b1[k]/w1[k]; region(t)=#{sorted hinges < t}. Per region:
//   edge:  W_r(t)=P_r + t*Q_r (32x32)  |  angle: f_r(t)=c_r + t*d_r (32)
// ===========================================================================
__global__ void setup_sort(const float* __restrict__ eW1, const float* __restrict__ eb1,
                           const float* __restrict__ aW1, const float* __restrict__ ab1,
                           float* __restrict__ ehs, float* __restrict__ ahs,
                           unsigned* __restrict__ emask, unsigned* __restrict__ amask)
{
    __shared__ float hv[64];
    __shared__ float sv[64];
    __shared__ int   sk[64];
    int tid = threadIdx.x;
    {
        int k = tid & 31;
        float w = (tid < 32) ? eW1[k] : aW1[k];
        float b = (tid < 32) ? eb1[k] : ab1[k];
        hv[tid] = (w != 0.f) ? (-b / w) : 1e30f;
    }
    __syncthreads();
    {
        int grp = tid >> 5, k = tid & 31;
        float v = hv[tid];
        int rank = 0;
        for (int j = 0; j < 32; ++j) {
            float u = hv[grp * 32 + j];
            rank += (u < v) || (u == v && j < k);
        }
        sv[grp * 32 + rank] = v;
        sk[grp * 32 + rank] = k;
    }
    __syncthreads();
    if (tid < 32) ehs[tid] = sv[tid];
    else          ahs[tid - 32] = sv[tid];
    if (tid == 0) {
        unsigned m = 0;
        for (int k = 0; k < 32; ++k) {
            float w = eW1[k], b = eb1[k];
            if (w < 0.f || (w == 0.f && b > 0.f)) m |= 1u << k;
        }
        emask[0] = m;
        for (int r = 1; r <= 32; ++r) {
            int k = sk[r - 1];
            float w = eW1[k];
            if (w > 0.f) m |= 1u << k; else if (w < 0.f) m &= ~(1u << k);
            emask[r] = m;
        }
    } else if (tid == 1) {
        unsigned m = 0;
        for (int k = 0; k < 32; ++k) {
            float w = aW1[k], b = ab1[k];
            if (w < 0.f || (w == 0.f && b > 0.f)) m |= 1u << k;
        }
        amask[0] = m;
        for (int r = 1; r <= 32; ++r) {
            int k = sk[32 + r - 1];
            float w = aW1[k];
            if (w > 0.f) m |= 1u << k; else if (w < 0.f) m &= ~(1u << k);
            amask[r] = m;
        }
    }
}

// ePQ layout (bf16): [r][o][kk], kk<32 -> P_r[kk,o], kk>=32 -> Q_r[kk-32,o]
// aCD layout (f32):  [r][0..31]=c_r, [r][32..63]=d_r
__global__ __launch_bounds__(256) void setup_tables(
    const float* __restrict__ eW1, const float* __restrict__ eb1,
    const float* __restrict__ eW2, const float* __restrict__ eb2,
    const float* __restrict__ aW1, const float* __restrict__ ab1,
    const float* __restrict__ aW2, const float* __restrict__ ab2,
    const unsigned* __restrict__ emask, const unsigned* __restrict__ amask,
    __hip_bfloat16* __restrict__ ePQ, float* __restrict__ aCD)
{
    int b = blockIdx.x, tid = threadIdx.x;
    if (b < NREG) {
        unsigned m = emask[b];
        for (int pos = tid; pos < 1024; pos += 256) {   // pos = i*32+o
            int i = pos >> 5, o = pos & 31;
            float P = eb2[pos];
            float Q = 0.f;
            for (int k = 0; k < 32; ++k) {
                if (m & (1u << k)) {
                    float w2 = eW2[k * 1024 + pos];
                    P += eb1[k] * w2;
                    Q += eW1[k] * w2;
                }
            }
            ePQ[b * 2048 + o * 64 + i]      = (__hip_bfloat16)P;
            ePQ[b * 2048 + o * 64 + 32 + i] = (__hip_bfloat16)Q;
        }
    } else if (tid < 32) {
        int r = b - NREG, o = tid;
        unsigned m = amask[r];
        float c = ab2[o], d = 0.f;
        for (int k = 0; k < 32; ++k) {
            if (m & (1u << k)) {
                float w2 = aW2[k * 32 + o];
                c += ab1[k] * w2;
                d += aW1[k] * w2;
            }
        }
        aCD[r * 64 + o]      = c;
        aCD[r * 64 + 32 + o] = d;
    }
}

// ===========================================================================
// Node-bucket counting sort (ids only). Blocks [0,EBLK): edges keyed by
// dst=edge_index[0][e]; blocks [EBLK,..): angles keyed by j=angle_index[1][a].
// ===========================================================================
__global__ __launch_bounds__(512) void bucket_hist(
    const int* __restrict__ edge_index, const int* __restrict__ angle_index,
    int* __restrict__ ebins, int* __restrict__ abins,
    int E, int A, int EBLK, int NB)
{
    __shared__ int lh[256];
    int tid = threadIdx.x, b = blockIdx.x;
    if (tid < 256) lh[tid] = 0;
    __syncthreads();
    if (b < EBLK) {
        int e = b * 512 + tid;
        if (e < E) atomicAdd(&lh[edge_index[e] / NPB], 1);
    } else {
        int a = (b - EBLK) * 512 + tid;
        if (a < A) atomicAdd(&lh[angle_index[A + a] / NPB], 1);
    }
    __syncthreads();
    int* g = (b < EBLK) ? ebins : abins;
    if (tid < NB && lh[tid]) atomicAdd(&g[tid], lh[tid]);
}

__global__ void scan_kernel(const int* __restrict__ ebins, const int* __restrict__ abins,
                            int* __restrict__ estarts, int* __restrict__ astarts, int NB)
{
    if (threadIdx.x == 0) {
        int s = 0;
        for (int i = 0; i < NB; ++i) { estarts[i] = s; s += ebins[i]; }
        estarts[NB] = s;
    } else if (threadIdx.x == 1) {
        int s = 0;
        for (int i = 0; i < NB; ++i) { astarts[i] = s; s += abins[i]; }
        astarts[NB] = s;
    }
}

__global__ __launch_bounds__(512) void bucket_scatter(
    const int* __restrict__ edge_index, const int* __restrict__ angle_index,
    const int* __restrict__ estarts, const int* __restrict__ astarts,
    int* __restrict__ ecur, int* __restrict__ acur,
    int* __restrict__ seid, int* __restrict__ said,
    int E, int A, int EBLK, int NB)
{
    __shared__ int lh[256], lb[256];
    int tid = threadIdx.x, b = blockIdx.x;
    if (tid < 256) lh[tid] = 0;
    __syncthreads();
    bool isEdge = (b < EBLK);
    int id = isEdge ? (b * 512 + tid) : ((b - EBLK) * 512 + tid);
    int lim = isEdge ? E : A;
    int bkt = 0, myo = 0;
    bool valid = (id < lim);
    if (valid) {
        bkt = (isEdge ? edge_index[id] : angle_index[A + id]) / NPB;
        myo = atomicAdd(&lh[bkt], 1);
    }
    __syncthreads();
    int* cur = isEdge ? ecur : acur;
    if (tid < NB) lb[tid] = lh[tid] ? atomicAdd(&cur[tid], lh[tid]) : 0;
    __syncthreads();
    if (valid) {
        const int* st = isEdge ? estarts : astarts;
        int* dst = isEdge ? seid : said;
        dst[st[bkt] + lb[bkt] + myo] = id;
    }
}

// ===========================================================================
// Consumer: one block per node bucket. LDS accumulator, zero global atomics.
// ===========================================================================
__global__ __launch_bounds__(1024) void consume(
    const float* __restrict__ x, const int* __restrict__ edge_index,
    const float* __restrict__ edge_attr,
    const int* __restrict__ angle_index, const float* __restrict__ angles,
    const __hip_bfloat16* __restrict__ ePQ, const float* __restrict__ aCD,
    const float* __restrict__ ehs, const float* __restrict__ ahs,
    const int* __restrict__ estarts, const int* __restrict__ astarts,
    const int* __restrict__ seid, const int* __restrict__ said,
    float* __restrict__ out, int E, int A, int N)
{
    __shared__ float sacc[NPB * 32];        // 25.6 KB node accumulator
    __shared__ float scd[NREG * 64];        // 8.45 KB angle c,d table
    __shared__ float she[32], sha[32];
    __shared__ int stmpe[ECAP], stmpr[ECAP];
    __shared__ int seids[ECAP];
    __shared__ int srcount[NREG], srstart[NREG + 1], srtile[NREG + 1], srcur[NREG];

    const int tid = threadIdx.x;
    const int b = blockIdx.x;
    const int base = b * NPB;

    for (int i = tid; i < NPB * 8; i += 1024) ((float4*)sacc)[i] = make_float4(0.f, 0.f, 0.f, 0.f);
    for (int i = tid; i < NREG * 64; i += 1024) scd[i] = aCD[i];
    if (tid < 32) she[tid] = ehs[tid];
    else if (tid < 64) sha[tid - 32] = ahs[tid - 32];
    __syncthreads();

    // ---------------- edge branch: in-LDS region sort + MFMA tiles ----------
    const int segb = estarts[b];
    const int cnt = estarts[b + 1] - segb;
    const int lane = tid & 63;
    const int q = lane >> 4, l15 = lane & 15, kb = q * 8;
    const int w = tid >> 6;

    for (int ch = 0; ch < cnt || ch == 0; ch += ECAP) {
        const int m = min(ECAP, cnt - ch);
        if (tid < NREG) srcount[tid] = 0;
        __syncthreads();
        for (int i = tid; i < m; i += 1024) {
            int e = seid[segb + ch + i];
            float t = edge_attr[e];
            int r = 0;
#pragma unroll
            for (int j = 0; j < 32; ++j) r += (t > she[j]) ? 1 : 0;
            stmpe[i] = e;
            stmpr[i] = r;
            atomicAdd(&srcount[r], 1);
        }
        __syncthreads();
        if (tid == 0) {
            int s = 0, pt = 0;
            for (int r = 0; r < NREG; ++r) {
                srstart[r] = s; srtile[r] = pt; srcur[r] = 0;
                s += srcount[r];
                pt += (srcount[r] + 15) >> 4;
            }
            srstart[NREG] = s; srtile[NREG] = pt;
        }
        __syncthreads();
        for (int i = tid; i < m; i += 1024) {
            int r = stmpr[i];
            int o = atomicAdd(&srcur[r], 1);
            seids[srstart[r] + o] = stmpe[i];
        }
        __syncthreads();

        const int T = srtile[NREG];
        for (int tau = w; tau < T; tau += 16) {
            int r = 0;
            while (srtile[r + 1] <= tau) ++r;
            const int toff = tau - srtile[r];
            const int rc = srcount[r], rs = srstart[r];

            const short* Tb = (const short*)ePQ + r * 2048;
            short8 B00 = *(const short8*)(Tb + l15 * 64 + kb);
            short8 B10 = *(const short8*)(Tb + l15 * 64 + 32 + kb);
            short8 B01 = *(const short8*)(Tb + (16 + l15) * 64 + kb);
            short8 B11 = *(const short8*)(Tb + (16 + l15) * 64 + 32 + kb);

            short8 a0 = (short8)0, a1 = (short8)0;
            const int s = toff * 16 + l15;
            if (s < rc) {
                int e = seids[rs + s];
                float t = edge_attr[e];
                int src = edge_index[E + e];
                const float* xp = x + src * IC + kb;
                float4 xlo = *(const float4*)xp;
                float4 xhi = *(const float4*)(xp + 4);
                float xf[8] = {xlo.x, xlo.y, xlo.z, xlo.w, xhi.x, xhi.y, xhi.z, xhi.w};
#pragma unroll
                for (int j = 0; j < 8; ++j) {
                    a0[j] = f2bf(xf[j]);
                    a1[j] = f2bf(t * xf[j]);
                }
            }
            f32x4 z = {0.f, 0.f, 0.f, 0.f};
            f32x4 acc0 = __builtin_amdgcn_mfma_f32_16x16x32_bf16(a0, B00, z, 0, 0, 0);
            acc0 = __builtin_amdgcn_mfma_f32_16x16x32_bf16(a1, B10, acc0, 0, 0, 0);
            f32x4 acc1 = __builtin_amdgcn_mfma_f32_16x16x32_bf16(a0, B01, z, 0, 0, 0);
            acc1 = __builtin_amdgcn_mfma_f32_16x16x32_bf16(a1, B11, acc1, 0, 0, 0);

#pragma unroll
            for (int rr = 0; rr < 4; ++rr) {
                const int s2 = toff * 16 + q * 4 + rr;
                if (s2 < rc) {
                    int e2 = seids[rs + s2];
                    int dl = edge_index[e2] - base;
                    atomicAdd(&sacc[dl * 32 + l15],      acc0[rr]);
                    atomicAdd(&sacc[dl * 32 + 16 + l15], acc1[rr]);
                }
            }
        }
        __syncthreads();
    }

    // ---------------- angle branch: table lookup + LDS atomic ---------------
    {
        const int ab0 = astarts[b];
        const int acnt = astarts[b + 1] - ab0;
        const int hw = tid >> 5, o = tid & 31;   // 32 half-waves per block
        for (int p = hw; p < acnt; p += 32) {
            int a = said[ab0 + p];
            float t = angles[a];
            int r = 0;
#pragma unroll
            for (int j = 0; j < 32; ++j) r += (t > sha[j]) ? 1 : 0;
            int n = angle_index[A + a] - base;
            float v = scd[r * 64 + o] + t * scd[r * 64 + 32 + o];
            atomicAdd(&sacc[n * 32 + o], v);
        }
    }
    __syncthreads();

    // ---------------- coalesced plain store (covers every node once) --------
    const int nh = min(NPB, N - base);
    float4* o4 = (float4*)(out + (size_t)base * 32);
    const float4* s4 = (const float4*)sacc;
    for (int i = tid; i < nh * 8; i += 1024) o4[i] = s4[i];
}

// ===========================================================================
// Fallback (round-1, known-good)
// ===========================================================================
__global__ void zero_kernel(float* __restrict__ out, int n) {
    int i = (blockIdx.x * blockDim.x + threadIdx.x) * 4;
    if (i + 3 < n) *(float4*)(out + i) = make_float4(0.f, 0.f, 0.f, 0.f);
    else for (int k = i; k < n; ++k) out[k] = 0.f;
}

__global__ __launch_bounds__(256) void edge_kernel_fb(
    const float* __restrict__ x, const int* __restrict__ edge_index,
    const float* __restrict__ edge_attr,
    const float* __restrict__ eW1, const float* __restrict__ eb1,
    const float* __restrict__ eW2, const float* __restrict__ eb2,
    float* __restrict__ out, int E)
{
    const int tid = threadIdx.x, lane = tid & 63;
    const int gwave = blockIdx.x * 4 + (tid >> 6);
    const int ot = gwave & 1, tile0 = gwave >> 1;
    const int tstride = (gridDim.x * 4) >> 1;
    const int q = lane >> 4, l15 = lane & 15, ocol = ot * 16 + l15;
    short8 Bf[33];
#pragma unroll
    for (int s = 0; s < 32; ++s) {
        short8 bb;
#pragma unroll
        for (int j = 0; j < 8; ++j) bb[j] = f2bf(eW2[s * 1024 + (q * 8 + j) * 32 + ocol]);
        Bf[s] = bb;
    }
    {
        short8 bb;
#pragma unroll
        for (int j = 0; j < 8; ++j) bb[j] = f2bf(eb2[(q * 8 + j) * 32 + ocol]);
        Bf[32] = bb;
    }
    const int numTiles = (E + 15) >> 4;
    for (int tile = tile0; tile < numTiles; tile += tstride) {
        const int e16 = tile << 4, eA = e16 + l15;
        const bool va = (eA < E);
        const int eAc = va ? eA : 0;
        const float t = va ? edge_attr[eAc] : 0.f;
        const int col = va ? edge_index[E + eAc] : 0;
        const float* xp = x + col * IC + q * 8;
        const float4 xlo = *(const float4*)(xp);
        const float4 xhi = *(const float4*)(xp + 4);
        float xf[8] = {xlo.x, xlo.y, xlo.z, xlo.w, xhi.x, xhi.y, xhi.z, xhi.w};
        f32x4 acc = {0.f, 0.f, 0.f, 0.f};
#pragma unroll
        for (int s = 0; s < 32; ++s) {
            float hs = t * eW1[s] + eb1[s];
            hs = hs > 0.f ? hs : 0.f;
            short8 a;
#pragma unroll
            for (int j = 0; j < 8; ++j) a[j] = f2bf(xf[j] * hs);
            acc = __builtin_amdgcn_mfma_f32_16x16x32_bf16(a, Bf[s], acc, 0, 0, 0);
        }
        {
            short8 a;
#pragma unroll
            for (int j = 0; j < 8; ++j) a[j] = f2bf(xf[j]);
            acc = __builtin_amdgcn_mfma_f32_16x16x32_bf16(a, Bf[32], acc, 0, 0, 0);
        }
        const int ebase = e16 + q * 4;
#pragma unroll
        for (int r = 0; r < 4; ++r) {
            const int er = ebase + r;
            if (er < E) unsafeAtomicAdd(out + edge_index[er] * OC + ocol, acc[r]);
        }
    }
}

__global__ __launch_bounds__(256) void angle_kernel_fb(
    const float* __restrict__ angles, const int* __restrict__ angle_index,
    const float* __restrict__ aW1, const float* __restrict__ ab1,
    const float* __restrict__ aW2, const float* __restrict__ ab2,
    float* __restrict__ out, int A)
{
    const int tid = threadIdx.x, lane = tid & 63;
    const int gwave = blockIdx.x * 4 + (tid >> 6);
    const int ot = gwave & 1, tile0 = gwave >> 1;
    const int tstride = (gridDim.x * 4) >> 1;
    const int q = lane >> 4, l15 = lane & 15, ocol = ot * 16 + l15;
    short8 Bf;
#pragma unroll
    for (int j = 0; j < 8; ++j) Bf[j] = f2bf(aW2[(q * 8 + j) * 32 + ocol]);
    const float bias = ab2[ocol];
    float w1[8], b1[8];
#pragma unroll
    for (int j = 0; j < 8; ++j) { w1[j] = aW1[q * 8 + j]; b1[j] = ab1[q * 8 + j]; }
    const int numTiles = (A + 15) >> 4;
    for (int tile = tile0; tile < numTiles; tile += tstride) {
        const int a16 = tile << 4, ai = a16 + l15;
        const float t = (ai < A) ? angles[ai] : 0.f;
        short8 a;
#pragma unroll
        for (int j = 0; j < 8; ++j) {
            float h = t * w1[j] + b1[j];
            h = h > 0.f ? h : 0.f;
            a[j] = f2bf(h);
        }
        f32x4 acc = {0.f, 0.f, 0.f, 0.f};
        acc = __builtin_amdgcn_mfma_f32_16x16x32_bf16(a, Bf, acc, 0, 0, 0);
        const int abase = a16 + q * 4;
#pragma unroll
        for (int r = 0; r < 4; ++r) {
            const int ar = abase + r;
            if (ar < A) unsafeAtomicAdd(out + angle_index[A + ar] * OC + ocol, acc[r] + bias);
        }
    }
}

// ===========================================================================
extern "C" void kernel_launch(void* const* d_in, const int* in_sizes, int n_in,
                              void* d_out, int out_size, void* d_ws, size_t ws_size,
                              hipStream_t stream)
{
    const float* x          = (const float*)d_in[0];
    const int*   edge_index = (const int*)d_in[1];
    const float* edge_attr  = (const float*)d_in[2];
    const int*   angle_index= (const int*)d_in[3];
    const float* angles     = (const float*)d_in[4];
    const float* eW1        = (const float*)d_in[5];
    const float* eb1        = (const float*)d_in[6];
    const float* eW2        = (const float*)d_in[7];
    const float* eb2        = (const float*)d_in[8];
    const float* aW1        = (const float*)d_in[9];
    const float* ab1        = (const float*)d_in[10];
    const float* aW2        = (const float*)d_in[11];
    const float* ab2        = (const float*)d_in[12];
    float* out = (float*)d_out;

    const int E = in_sizes[1] / 2;
    const int A = in_sizes[3] / 3;
    const int N = out_size / OC;
    const int NB = (N + NPB - 1) / NPB;

    size_t off = 0;
    auto carve = [&](size_t bytes) {
        size_t o = off;
        off += (bytes + 255) & ~(size_t)255;
        return o;
    };
    char* wsb = (char*)d_ws;
    size_t o_ePQ   = carve((size_t)NREG * 2048 * 2);
    size_t o_aCD   = carve((size_t)NREG * 64 * 4);
    size_t o_ehs   = carve(128);
    size_t o_ahs   = carve(128);
    size_t o_emask = carve(NREG * 4);
    size_t o_amask = carve(NREG * 4);
    size_t o_meta  = carve((size_t)(6 * NB + 2) * 4);
    size_t o_seid  = carve((size_t)E * 4);
    size_t o_said  = carve((size_t)A * 4);
    size_t needed = off;

    if (needed <= ws_size && NB <= 256) {
        __hip_bfloat16* ePQ = (__hip_bfloat16*)(wsb + o_ePQ);
        float* aCD   = (float*)(wsb + o_aCD);
        float* ehs   = (float*)(wsb + o_ehs);
        float* ahs   = (float*)(wsb + o_ahs);
        unsigned* emask = (unsigned*)(wsb + o_emask);
        unsigned* amask = (unsigned*)(wsb + o_amask);
        int* meta    = (int*)(wsb + o_meta);
        int* ebins   = meta;
        int* estarts = meta + NB;
        int* ecur    = meta + 2 * NB + 1;
        int* abins   = meta + 3 * NB + 1;
        int* astarts = meta + 4 * NB + 1;
        int* acur    = meta + 5 * NB + 2;
        int* seid    = (int*)(wsb + o_seid);
        int* said    = (int*)(wsb + o_said);

        hipMemsetAsync(meta, 0, (size_t)(6 * NB + 2) * 4, stream);

        setup_sort<<<1, 64, 0, stream>>>(eW1, eb1, aW1, ab1, ehs, ahs, emask, amask);
        setup_tables<<<2 * NREG, 256, 0, stream>>>(eW1, eb1, eW2, eb2,
                                                   aW1, ab1, aW2, ab2,
                                                   emask, amask, ePQ, aCD);
        const int EBLK = (E + 511) / 512, ABLK = (A + 511) / 512;
        bucket_hist<<<EBLK + ABLK, 512, 0, stream>>>(edge_index, angle_index,
                                                     ebins, abins, E, A, EBLK, NB);
        scan_kernel<<<1, 64, 0, stream>>>(ebins, abins, estarts, astarts, NB);
        bucket_scatter<<<EBLK + ABLK, 512, 0, stream>>>(edge_index, angle_index,
                                                        estarts, astarts, ecur, acur,
                                                        seid, said, E, A, EBLK, NB);
        consume<<<NB, 1024, 0, stream>>>(x, edge_index, edge_attr,
                                         angle_index, angles,
                                         ePQ, aCD, ehs, ahs,
                                         estarts, astarts, seid, said,
                                         out, E, A, N);
    } else {
        zero_kernel<<<(out_size / 4 + 255) / 256, 256, 0, stream>>>(out, out_size);
        edge_kernel_fb<<<1024, 256, 0, stream>>>(x, edge_index, edge_attr,
                                                 eW1, eb1, eW2, eb2, out, E);
        angle_kernel_fb<<<1024, 256, 0, stream>>>(angles, angle_index,
                                                  aW1, ab1, aW2, ab2, out, A);
    }
}

// Round 5
// 288.206 us; speedup vs baseline: 1.1325x; 1.1325x over previous
//
#include <hip/hip_runtime.h>
#include <hip/hip_bf16.h>
#include <stdint.h>

#define IC 32
#define OC 32
#define NREG 33      // 32 hinges -> 33 piecewise-linear regions
#define NPB 100      // nodes per angle bucket
#define MAXB 512     // max angle buckets (LDS hist width)
#define ACH 512      // angle consumer staging chunk

typedef __attribute__((ext_vector_type(8))) short short8;
typedef __attribute__((ext_vector_type(4))) float f32x4;

static __device__ __forceinline__ short f2bf(float f) {
    __bf16 b = (__bf16)f;
    return __builtin_bit_cast(short, b);
}
static __device__ __forceinline__ float bf2f(short s) {
    return (float)__builtin_bit_cast(__bf16, s);
}

// ===========================================================================
// Piecewise-linear setup (validated R2/R3):
//   edge:  W_r(t)=P_r + t*Q_r (32x32)  |  angle: f_r(t)=c_r + t*d_r (32)
// ===========================================================================
__global__ void setup_sort(const float* __restrict__ eW1, const float* __restrict__ eb1,
                           const float* __restrict__ aW1, const float* __restrict__ ab1,
                           float* __restrict__ ehs, float* __restrict__ ahs,
                           unsigned* __restrict__ emask, unsigned* __restrict__ amask)
{
    __shared__ float hv[64];
    __shared__ float sv[64];
    __shared__ int   sk[64];
    int tid = threadIdx.x;
    {
        int k = tid & 31;
        float w = (tid < 32) ? eW1[k] : aW1[k];
        float b = (tid < 32) ? eb1[k] : ab1[k];
        hv[tid] = (w != 0.f) ? (-b / w) : 1e30f;
    }
    __syncthreads();
    {
        int grp = tid >> 5, k = tid & 31;
        float v = hv[tid];
        int rank = 0;
        for (int j = 0; j < 32; ++j) {
            float u = hv[grp * 32 + j];
            rank += (u < v) || (u == v && j < k);
        }
        sv[grp * 32 + rank] = v;
        sk[grp * 32 + rank] = k;
    }
    __syncthreads();
    if (tid < 32) ehs[tid] = sv[tid];
    else          ahs[tid - 32] = sv[tid];
    if (tid == 0) {
        unsigned m = 0;
        for (int k = 0; k < 32; ++k) {
            float w = eW1[k], b = eb1[k];
            if (w < 0.f || (w == 0.f && b > 0.f)) m |= 1u << k;
        }
        emask[0] = m;
        for (int r = 1; r <= 32; ++r) {
            int k = sk[r - 1];
            float w = eW1[k];
            if (w > 0.f) m |= 1u << k; else if (w < 0.f) m &= ~(1u << k);
            emask[r] = m;
        }
    } else if (tid == 1) {
        unsigned m = 0;
        for (int k = 0; k < 32; ++k) {
            float w = aW1[k], b = ab1[k];
            if (w < 0.f || (w == 0.f && b > 0.f)) m |= 1u << k;
        }
        amask[0] = m;
        for (int r = 1; r <= 32; ++r) {
            int k = sk[32 + r - 1];
            float w = aW1[k];
            if (w > 0.f) m |= 1u << k; else if (w < 0.f) m &= ~(1u << k);
            amask[r] = m;
        }
    }
}

// ePQ (bf16): [r][o][kk], kk<32 -> P_r[kk,o], kk>=32 -> Q_r[kk-32,o]
// aCD (f32):  [r][0..31]=c_r, [r][32..63]=d_r
__global__ __launch_bounds__(256) void setup_tables(
    const float* __restrict__ eW1, const float* __restrict__ eb1,
    const float* __restrict__ eW2, const float* __restrict__ eb2,
    const float* __restrict__ aW1, const float* __restrict__ ab1,
    const float* __restrict__ aW2, const float* __restrict__ ab2,
    const unsigned* __restrict__ emask, const unsigned* __restrict__ amask,
    __hip_bfloat16* __restrict__ ePQ, float* __restrict__ aCD)
{
    int b = blockIdx.x, tid = threadIdx.x;
    if (b < NREG) {
        unsigned m = emask[b];
        for (int pos = tid; pos < 1024; pos += 256) {   // pos = i*32+o
            int i = pos >> 5, o = pos & 31;
            float P = eb2[pos];
            float Q = 0.f;
            for (int k = 0; k < 32; ++k) {
                if (m & (1u << k)) {
                    float w2 = eW2[k * 1024 + pos];
                    P += eb1[k] * w2;
                    Q += eW1[k] * w2;
                }
            }
            ePQ[b * 2048 + o * 64 + i]      = (__hip_bfloat16)P;
            ePQ[b * 2048 + o * 64 + 32 + i] = (__hip_bfloat16)Q;
        }
    } else if (tid < 32) {
        int r = b - NREG, o = tid;
        unsigned m = amask[r];
        float c = ab2[o], d = 0.f;
        for (int k = 0; k < 32; ++k) {
            if (m & (1u << k)) {
                float w2 = aW2[k * 32 + o];
                c += ab1[k] * w2;
                d += aW1[k] * w2;
            }
        }
        aCD[r * 64 + o]      = c;
        aCD[r * 64 + 32 + o] = d;
    }
}

// --- x -> bf16 once (halves gather bytes; A-frag loads directly) ----------
__global__ __launch_bounds__(256) void x_to_bf16(const float* __restrict__ x,
                                                 __hip_bfloat16* __restrict__ xbf, int n)
{
    int i = (blockIdx.x * 256 + threadIdx.x) * 4;
    if (i + 3 < n) {
        float4 v = *(const float4*)(x + i);
        xbf[i]     = (__hip_bfloat16)v.x;
        xbf[i + 1] = (__hip_bfloat16)v.y;
        xbf[i + 2] = (__hip_bfloat16)v.z;
        xbf[i + 3] = (__hip_bfloat16)v.w;
    } else {
        for (int k = i; k < n; ++k) xbf[k] = (__hip_bfloat16)x[k];
    }
}

// ===========================================================================
// Dual counting sort: edges by PW-region (blocks < EBLK), angles by node
// bucket (rest). hist -> scan -> scatter (scatter pre-gathers payloads).
// ===========================================================================
__global__ __launch_bounds__(512) void hist_kernel(
    const int* __restrict__ edge_index, const float* __restrict__ edge_attr,
    const int* __restrict__ angle_index, const float* __restrict__ ehs,
    int* __restrict__ ebins, int* __restrict__ abins,
    int E, int A, int EBLK, int NBA)
{
    __shared__ int lh[MAXB];
    __shared__ float she[32];
    int tid = threadIdx.x, b = blockIdx.x;
    if (tid < 32) she[tid] = ehs[tid];
    lh[tid] = 0;
    __syncthreads();
    if (b < EBLK) {
        int e = b * 512 + tid;
        if (e < E) {
            float t = edge_attr[e];
            int r = 0;
#pragma unroll
            for (int j = 0; j < 32; ++j) r += (t > she[j]) ? 1 : 0;
            atomicAdd(&lh[r], 1);
        }
        __syncthreads();
        if (tid < NREG && lh[tid]) atomicAdd(&ebins[tid], lh[tid]);
    } else {
        int a = (b - EBLK) * 512 + tid;
        if (a < A) atomicAdd(&lh[angle_index[A + a] / NPB], 1);
        __syncthreads();
        if (tid < NBA && lh[tid]) atomicAdd(&abins[tid], lh[tid]);
    }
}

__global__ __launch_bounds__(512) void scan_kernel2(
    const int* __restrict__ ebins, int* __restrict__ estarts,
    const int* __restrict__ abins, int* __restrict__ astarts, int NBA)
{
    __shared__ int arr[MAXB];
    int tid = threadIdx.x;
    if (tid == 0) {   // 33 bins, 16-aligned starts -> region-pure MFMA tiles
        int s = 0;
        for (int r = 0; r < NREG; ++r) { estarts[r] = s; s += (ebins[r] + 15) & ~15; }
        estarts[NREG] = s;
    }
    int av = (tid < NBA) ? abins[tid] : 0;
    arr[tid] = av;
    __syncthreads();
    for (int off = 1; off < MAXB; off <<= 1) {
        int v = (tid >= off) ? arr[tid - off] : 0;
        __syncthreads();
        arr[tid] += v;
        __syncthreads();
    }
    if (tid < NBA) {
        astarts[tid] = arr[tid] - av;
        if (tid == NBA - 1) astarts[NBA] = arr[tid];
    }
}

__global__ __launch_bounds__(512) void scatter_kernel(
    const int* __restrict__ edge_index, const float* __restrict__ edge_attr,
    const int* __restrict__ angle_index, const float* __restrict__ angles,
    const float* __restrict__ ehs, const float* __restrict__ ahs,
    const int* __restrict__ estarts, int* __restrict__ ecur,
    const int* __restrict__ astarts, int* __restrict__ acur,
    float* __restrict__ se_t, int* __restrict__ se_src, int* __restrict__ se_dst,
    float* __restrict__ sa_t, int* __restrict__ sa_p,
    int E, int A, int EBLK, int NBA)
{
    __shared__ int lh[MAXB], lb[MAXB];
    __shared__ float sh[32];
    int tid = threadIdx.x, b = blockIdx.x;
    bool isE = (b < EBLK);
    if (tid < 32) sh[tid] = isE ? ehs[tid] : ahs[tid];
    lh[tid] = 0;
    __syncthreads();
    if (isE) {
        int e = b * 512 + tid;
        int r = 0, myo = 0; float t = 0.f;
        bool v = (e < E);
        if (v) {
            t = edge_attr[e];
#pragma unroll
            for (int j = 0; j < 32; ++j) r += (t > sh[j]) ? 1 : 0;
            myo = atomicAdd(&lh[r], 1);
        }
        __syncthreads();
        if (tid < NREG) lb[tid] = lh[tid] ? atomicAdd(&ecur[tid], lh[tid]) : 0;
        __syncthreads();
        if (v) {
            int pos = estarts[r] + lb[r] + myo;
            se_t[pos]   = t;
            se_src[pos] = edge_index[E + e];   // source node (gathered here)
            se_dst[pos] = edge_index[e];       // destination node
        }
    } else {
        int a = (b - EBLK) * 512 + tid;
        int bkt = 0, myo = 0, pk = 0; float t = 0.f;
        bool v = (a < A);
        if (v) {
            t = angles[a];
            int r = 0;
#pragma unroll
            for (int j = 0; j < 32; ++j) r += (t > sh[j]) ? 1 : 0;
            int n = angle_index[A + a];
            bkt = n / NPB;
            pk = (n - bkt * NPB) * 64 + r;     // packed local-node | region
            myo = atomicAdd(&lh[bkt], 1);
        }
        __syncthreads();
        if (tid < NBA) lb[tid] = lh[tid] ? atomicAdd(&acur[tid], lh[tid]) : 0;
        __syncthreads();
        if (v) {
            int pos = astarts[bkt] + lb[bkt] + myo;
            sa_t[pos] = t;
            sa_p[pos] = pk;
        }
    }
}

// --- precompute tile -> region (kills the per-wave serial search) ----------
__global__ __launch_bounds__(256) void tilereg_kernel(
    const int* __restrict__ ebins, const int* __restrict__ estarts,
    int* __restrict__ tileReg, int Tmax)
{
    int tau = blockIdx.x * 256 + threadIdx.x;
    if (tau >= Tmax) return;
    int s = tau * 16, reg = -1;
    for (int r = 0; r < NREG; ++r)
        if (s >= estarts[r] && s < estarts[r] + ebins[r]) reg = r;
    tileReg[tau] = reg;
}

// ===========================================================================
// Edge GEMM: wave = 16 edges x 32 outputs, K=64 (x | t*x) vs (P_r ; Q_r).
// All list reads coalesced; only x gather is random; scatter = global atomics.
// ===========================================================================
__global__ __launch_bounds__(256) void edge_gemm(
    const __hip_bfloat16* __restrict__ xbf,
    const float* __restrict__ se_t, const int* __restrict__ se_src,
    const int* __restrict__ se_dst,
    const int* __restrict__ tileReg, const __hip_bfloat16* __restrict__ ePQ,
    float* __restrict__ out, int Tmax)
{
    int tid = threadIdx.x, lane = tid & 63;
    int tau = blockIdx.x * 4 + (tid >> 6);
    if (tau >= Tmax) return;
    int r = tileReg[tau];
    if (r < 0) return;

    int q = lane >> 4, l15 = lane & 15, kb = q * 8;
    const short* Tb = (const short*)ePQ + r * 2048;
    short8 B00 = *(const short8*)(Tb + l15 * 64 + kb);
    short8 B10 = *(const short8*)(Tb + l15 * 64 + 32 + kb);
    short8 B01 = *(const short8*)(Tb + (16 + l15) * 64 + kb);
    short8 B11 = *(const short8*)(Tb + (16 + l15) * 64 + 32 + kb);

    int s = tau * 16 + l15;
    int dst = se_dst[s];                 // -1 for padding slots
    float t = se_t[s];
    int src = (dst >= 0) ? se_src[s] : 0;
    if (dst < 0) t = 0.f;
    short8 a0 = *(const short8*)((const short*)xbf + src * IC + kb);
    short8 a1;
#pragma unroll
    for (int j = 0; j < 8; ++j) a1[j] = f2bf(t * bf2f(a0[j]));

    f32x4 z = {0.f, 0.f, 0.f, 0.f};
    f32x4 acc0 = __builtin_amdgcn_mfma_f32_16x16x32_bf16(a0, B00, z, 0, 0, 0);
    acc0 = __builtin_amdgcn_mfma_f32_16x16x32_bf16(a1, B10, acc0, 0, 0, 0);
    f32x4 acc1 = __builtin_amdgcn_mfma_f32_16x16x32_bf16(a0, B01, z, 0, 0, 0);
    acc1 = __builtin_amdgcn_mfma_f32_16x16x32_bf16(a1, B11, acc1, 0, 0, 0);

#pragma unroll
    for (int rr = 0; rr < 4; ++rr) {
        int s2 = tau * 16 + q * 4 + rr;
        int d2 = se_dst[s2];
        if (d2 >= 0) {
            unsafeAtomicAdd(out + d2 * OC + l15,      acc0[rr]);
            unsafeAtomicAdd(out + d2 * OC + 16 + l15, acc1[rr]);
        }
    }
}

// ===========================================================================
// Angle consumer: block per 100-node bucket; everything staged in LDS;
// half-wave per angle; one plain coalesced += write (after edge_gemm).
// ===========================================================================
__global__ __launch_bounds__(256) void angle_consume(
    const float* __restrict__ sa_t, const int* __restrict__ sa_p,
    const int* __restrict__ astarts, const float* __restrict__ aCD,
    float* __restrict__ out, int N)
{
    __shared__ float sacc[NPB * 32];     // 12.8 KB
    __shared__ float scd[NREG * 64];     // 8.45 KB
    __shared__ float st_t[ACH];
    __shared__ int   st_p[ACH];
    int tid = threadIdx.x, b = blockIdx.x;
    int base = b * NPB;

    for (int i = tid; i < NPB * 8; i += 256) ((float4*)sacc)[i] = make_float4(0.f, 0.f, 0.f, 0.f);
    for (int i = tid; i < NREG * 64; i += 256) scd[i] = aCD[i];
    __syncthreads();

    int a0 = astarts[b], cnt = astarts[b + 1] - a0;
    int hw = tid >> 5, o = tid & 31;
    for (int ch = 0; ch < cnt; ch += ACH) {
        int m = min(ACH, cnt - ch);
        for (int i = tid; i < m; i += 256) {
            st_t[i] = sa_t[a0 + ch + i];
            st_p[i] = sa_p[a0 + ch + i];
        }
        __syncthreads();
        for (int p = hw; p < m; p += 8) {
            float t = st_t[p];
            int pk = st_p[p];
            int n = pk >> 6, r = pk & 63;
            float v = scd[r * 64 + o] + t * scd[r * 64 + 32 + o];
            atomicAdd(&sacc[n * 32 + o], v);
        }
        __syncthreads();
    }

    int nh = min(NPB, N - base);
    float4* o4 = (float4*)(out + (size_t)base * 32);
    const float4* s4 = (const float4*)sacc;
    for (int i = tid; i < nh * 8; i += 256) {
        float4 a = o4[i], sv = s4[i];
        o4[i] = make_float4(a.x + sv.x, a.y + sv.y, a.z + sv.z, a.w + sv.w);
    }
}

// ===========================================================================
// Fallback (round-1, known-good 194us)
// ===========================================================================
__global__ void zero_kernel(float* __restrict__ out, int n) {
    int i = (blockIdx.x * blockDim.x + threadIdx.x) * 4;
    if (i + 3 < n) *(float4*)(out + i) = make_float4(0.f, 0.f, 0.f, 0.f);
    else for (int k = i; k < n; ++k) out[k] = 0.f;
}

__global__ __launch_bounds__(256) void edge_kernel_fb(
    const float* __restrict__ x, const int* __restrict__ edge_index,
    const float* __restrict__ edge_attr,
    const float* __restrict__ eW1, const float* __restrict__ eb1,
    const float* __restrict__ eW2, const float* __restrict__ eb2,
    float* __restrict__ out, int E)
{
    const int tid = threadIdx.x, lane = tid & 63;
    const int gwave = blockIdx.x * 4 + (tid >> 6);
    const int ot = gwave & 1, tile0 = gwave >> 1;
    const int tstride = (gridDim.x * 4) >> 1;
    const int q = lane >> 4, l15 = lane & 15, ocol = ot * 16 + l15;
    short8 Bf[33];
#pragma unroll
    for (int s = 0; s < 32; ++s) {
        short8 bb;
#pragma unroll
        for (int j = 0; j < 8; ++j) bb[j] = f2bf(eW2[s * 1024 + (q * 8 + j) * 32 + ocol]);
        Bf[s] = bb;
    }
    {
        short8 bb;
#pragma unroll
        for (int j = 0; j < 8; ++j) bb[j] = f2bf(eb2[(q * 8 + j) * 32 + ocol]);
        Bf[32] = bb;
    }
    const int numTiles = (E + 15) >> 4;
    for (int tile = tile0; tile < numTiles; tile += tstride) {
        const int e16 = tile << 4, eA = e16 + l15;
        const bool va = (eA < E);
        const int eAc = va ? eA : 0;
        const float t = va ? edge_attr[eAc] : 0.f;
        const int col = va ? edge_index[E + eAc] : 0;
        const float* xp = x + col * IC + q * 8;
        const float4 xlo = *(const float4*)(xp);
        const float4 xhi = *(const float4*)(xp + 4);
        float xf[8] = {xlo.x, xlo.y, xlo.z, xlo.w, xhi.x, xhi.y, xhi.z, xhi.w};
        f32x4 acc = {0.f, 0.f, 0.f, 0.f};
#pragma unroll
        for (int s = 0; s < 32; ++s) {
            float hs = t * eW1[s] + eb1[s];
            hs = hs > 0.f ? hs : 0.f;
            short8 a;
#pragma unroll
            for (int j = 0; j < 8; ++j) a[j] = f2bf(xf[j] * hs);
            acc = __builtin_amdgcn_mfma_f32_16x16x32_bf16(a, Bf[s], acc, 0, 0, 0);
        }
        {
            short8 a;
#pragma unroll
            for (int j = 0; j < 8; ++j) a[j] = f2bf(xf[j]);
            acc = __builtin_amdgcn_mfma_f32_16x16x32_bf16(a, Bf[32], acc, 0, 0, 0);
        }
        const int ebase = e16 + q * 4;
#pragma unroll
        for (int r = 0; r < 4; ++r) {
            const int er = ebase + r;
            if (er < E) unsafeAtomicAdd(out + edge_index[er] * OC + ocol, acc[r]);
        }
    }
}

__global__ __launch_bounds__(256) void angle_kernel_fb(
    const float* __restrict__ angles, const int* __restrict__ angle_index,
    const float* __restrict__ aW1, const float* __restrict__ ab1,
    const float* __restrict__ aW2, const float* __restrict__ ab2,
    float* __restrict__ out, int A)
{
    const int tid = threadIdx.x, lane = tid & 63;
    const int gwave = blockIdx.x * 4 + (tid >> 6);
    const int ot = gwave & 1, tile0 = gwave >> 1;
    const int tstride = (gridDim.x * 4) >> 1;
    const int q = lane >> 4, l15 = lane & 15, ocol = ot * 16 + l15;
    short8 Bf;
#pragma unroll
    for (int j = 0; j < 8; ++j) Bf[j] = f2bf(aW2[(q * 8 + j) * 32 + ocol]);
    const float bias = ab2[ocol];
    float w1[8], b1[8];
#pragma unroll
    for (int j = 0; j < 8; ++j) { w1[j] = aW1[q * 8 + j]; b1[j] = ab1[q * 8 + j]; }
    const int numTiles = (A + 15) >> 4;
    for (int tile = tile0; tile < numTiles; tile += tstride) {
        const int a16 = tile << 4, ai = a16 + l15;
        const float t = (ai < A) ? angles[ai] : 0.f;
        short8 a;
#pragma unroll
        for (int j = 0; j < 8; ++j) {
            float h = t * w1[j] + b1[j];
            h = h > 0.f ? h : 0.f;
            a[j] = f2bf(h);
        }
        f32x4 acc = {0.f, 0.f, 0.f, 0.f};
        acc = __builtin_amdgcn_mfma_f32_16x16x32_bf16(a, Bf, acc, 0, 0, 0);
        const int abase = a16 + q * 4;
#pragma unroll
        for (int r = 0; r < 4; ++r) {
            const int ar = abase + r;
            if (ar < A) unsafeAtomicAdd(out + angle_index[A + ar] * OC + ocol, acc[r] + bias);
        }
    }
}

// ===========================================================================
extern "C" void kernel_launch(void* const* d_in, const int* in_sizes, int n_in,
                              void* d_out, int out_size, void* d_ws, size_t ws_size,
                              hipStream_t stream)
{
    const float* x          = (const float*)d_in[0];
    const int*   edge_index = (const int*)d_in[1];
    const float* edge_attr  = (const float*)d_in[2];
    const int*   angle_index= (const int*)d_in[3];
    const float* angles     = (const float*)d_in[4];
    const float* eW1        = (const float*)d_in[5];
    const float* eb1        = (const float*)d_in[6];
    const float* eW2        = (const float*)d_in[7];
    const float* eb2        = (const float*)d_in[8];
    const float* aW1        = (const float*)d_in[9];
    const float* ab1        = (const float*)d_in[10];
    const float* aW2        = (const float*)d_in[11];
    const float* ab2        = (const float*)d_in[12];
    float* out = (float*)d_out;

    const int E = in_sizes[1] / 2;
    const int A = in_sizes[3] / 3;
    const int N = out_size / OC;
    const int NBA  = (N + NPB - 1) / NPB;
    const int Smax = E + 16 * NREG;              // sorted edge slots (16-aligned buckets)
    const int Tmax = (E + 15) / 16 + NREG + 1;   // max MFMA tiles
    const int EBLK = (E + 511) / 512, ABLK = (A + 511) / 512;

    // meta layout (ints), ONE set of constants used for alloc, memset & ptrs:
    //   [0..32]    ebins      (33, at OFF_EB=0)
    //   [40..73]   estarts    (34, at OFF_ES=40)
    //   [80..112]  ecur       (33, at OFF_EC=80)
    //   [120..)    abins(NBA) | astarts(NBA+1) | acur(NBA)
    const int OFF_EB = 0, OFF_ES = 40, OFF_EC = 80, OFF_AB = 120;
    const int METAI  = OFF_AB + NBA + (NBA + 1) + NBA + 8;   // total ints

    size_t off = 0;
    auto carve = [&](size_t bytes) {
        size_t o = off;
        off += (bytes + 255) & ~(size_t)255;
        return o;
    };
    char* wsb = (char*)d_ws;
    size_t o_ePQ   = carve((size_t)NREG * 2048 * 2);
    size_t o_aCD   = carve((size_t)NREG * 64 * 4);
    size_t o_ehs   = carve(128);
    size_t o_ahs   = carve(128);
    size_t o_emask = carve(NREG * 4);
    size_t o_amask = carve(NREG * 4);
    size_t o_meta  = carve((size_t)METAI * 4);
    size_t o_xbf   = carve((size_t)N * IC * 2);
    size_t o_treg  = carve((size_t)Tmax * 4);
    size_t o_set   = carve((size_t)Smax * 4);
    size_t o_ses   = carve((size_t)Smax * 4);
    size_t o_sed   = carve((size_t)Smax * 4);
    size_t o_sat   = carve((size_t)A * 4);
    size_t o_sap   = carve((size_t)A * 4);
    size_t needed = off;

    if (needed <= ws_size && NBA >= 1 && NBA <= MAXB) {
        __hip_bfloat16* ePQ = (__hip_bfloat16*)(wsb + o_ePQ);
        float* aCD   = (float*)(wsb + o_aCD);
        float* ehs   = (float*)(wsb + o_ehs);
        float* ahs   = (float*)(wsb + o_ahs);
        unsigned* emask = (unsigned*)(wsb + o_emask);
        unsigned* amask = (unsigned*)(wsb + o_amask);
        int* meta    = (int*)(wsb + o_meta);
        int* ebins   = meta + OFF_EB;
        int* estarts = meta + OFF_ES;
        int* ecur    = meta + OFF_EC;
        int* abins   = meta + OFF_AB;
        int* astarts = abins + NBA;
        int* acur    = astarts + NBA + 1;
        __hip_bfloat16* xbf = (__hip_bfloat16*)(wsb + o_xbf);
        int*   tileReg = (int*)(wsb + o_treg);
        float* se_t  = (float*)(wsb + o_set);
        int*   se_src= (int*)(wsb + o_ses);
        int*   se_dst= (int*)(wsb + o_sed);
        float* sa_t  = (float*)(wsb + o_sat);
        int*   sa_p  = (int*)(wsb + o_sap);

        hipMemsetAsync(out, 0, (size_t)out_size * 4, stream);
        hipMemsetAsync(meta, 0, (size_t)METAI * 4, stream);     // covers ALL of meta
        hipMemsetAsync(se_dst, 0xFF, (size_t)Smax * 4, stream); // -1 = padding

        setup_sort<<<1, 64, 0, stream>>>(eW1, eb1, aW1, ab1, ehs, ahs, emask, amask);
        setup_tables<<<2 * NREG, 256, 0, stream>>>(eW1, eb1, eW2, eb2,
                                                   aW1, ab1, aW2, ab2,
                                                   emask, amask, ePQ, aCD);
        x_to_bf16<<<(N * IC / 4 + 255) / 256, 256, 0, stream>>>(x, xbf, N * IC);
        hist_kernel<<<EBLK + ABLK, 512, 0, stream>>>(edge_index, edge_attr, angle_index,
                                                     ehs, ebins, abins, E, A, EBLK, NBA);
        scan_kernel2<<<1, 512, 0, stream>>>(ebins, estarts, abins, astarts, NBA);
        scatter_kernel<<<EBLK + ABLK, 512, 0, stream>>>(edge_index, edge_attr,
                                                        angle_index, angles, ehs, ahs,
                                                        estarts, ecur, astarts, acur,
                                                        se_t, se_src, se_dst, sa_t, sa_p,
                                                        E, A, EBLK, NBA);
        tilereg_kernel<<<(Tmax + 255) / 256, 256, 0, stream>>>(ebins, estarts, tileReg, Tmax);
        edge_gemm<<<(Tmax + 3) / 4, 256, 0, stream>>>(xbf, se_t, se_src, se_dst,
                                                      tileReg, ePQ, out, Tmax);
        angle_consume<<<NBA, 256, 0, stream>>>(sa_t, sa_p, astarts, aCD, out, N);
    } else {
        zero_kernel<<<(out_size / 4 + 255) / 256, 256, 0, stream>>>(out, out_size);
        edge_kernel_fb<<<1024, 256, 0, stream>>>(x, edge_index, edge_attr,
                                                 eW1, eb1, eW2, eb2, out, E);
        angle_kernel_fb<<<1024, 256, 0, stream>>>(angles, angle_index,
                                                  aW1, ab1, aW2, ab2, out, A);
    }
}